// Round 9
// baseline (276.266 us; speedup 1.0000x reference)
//
#include <hip/hip_runtime.h>
#include <math.h>

// Problem constants
constexpr int D     = 1024;
constexpr int NH    = 16;
constexpr int HD    = 64;
constexpr int SEQ   = 2048;
constexpr int BATCH = 4;
constexpr int NTOK  = BATCH * SEQ;   // 8192 rows

typedef short s16x8 __attribute__((ext_vector_type(8)));
typedef short s16x4 __attribute__((ext_vector_type(4)));
typedef float f32x4 __attribute__((ext_vector_type(4)));
typedef unsigned short u16;
typedef unsigned int   u32;

#if __has_builtin(__builtin_amdgcn_exp2f)
#define EXP2(x) __builtin_amdgcn_exp2f(x)
#else
#define EXP2(x) exp2f(x)
#endif

__device__ __forceinline__ short f2bf(float f) {
    unsigned u = __float_as_uint(f);
    unsigned r = (u + 0x7FFFu + ((u >> 16) & 1u)) >> 16;   // RNE
    return (short)r;
}
__device__ __forceinline__ float bf2f(u16 s) {
    return __uint_as_float(((unsigned)s) << 16);
}

// pack hi16(f1)|hi16(f0) -> one u32 (lo = f0) via v_perm_b32
// NOTE (round-4 post-mortem): v_cvt_pk_bf16_f32 inline-asm replacement broke
// (mixed-sign garbage in P, absmax 4.9e3). Do NOT reintroduce without an
// isolated probe. This 3-instr sequence is proven.
__device__ __forceinline__ u32 pack_bf16_pair(float f0, float f1) {
    u32 a = __float_as_uint(f1) + 0x8000u;   // round half up
    u32 b = __float_as_uint(f0) + 0x8000u;
    return __builtin_amdgcn_perm(a, b, 0x07060302u);
}

__device__ __forceinline__ void async_lds16(const void* g, void* l) {
    __builtin_amdgcn_global_load_lds(
        (const __attribute__((address_space(1))) unsigned int*)g,
        (__attribute__((address_space(3))) unsigned int*)l, 16, 0, 0);
}

// swizzled fragment read for 64-u16 (128B) LDS rows: 2-way bank spread (free)
__device__ __forceinline__ s16x8 rdfrag(const u16* lds, int row, int kk, int quad) {
    int byte = row * 128 + ((kk * 64 + quad * 16) ^ ((row & 7) << 4));
    return *(const s16x8*)((const char*)lds + byte);
}

// ---------------------------------------------------------------------------
// Reductions (wave = 64)
// ---------------------------------------------------------------------------
__device__ __forceinline__ float block_reduce_sum(float v, float* red) {
    int lane = threadIdx.x & 63, wid = threadIdx.x >> 6;
    #pragma unroll
    for (int off = 32; off > 0; off >>= 1) v += __shfl_down(v, off, 64);
    if (lane == 0) red[wid] = v;
    __syncthreads();
    float r = red[0] + red[1] + red[2] + red[3];
    __syncthreads();
    return r;
}

// ---------------------------------------------------------------------------
// 1) Fused prep: LayerNorm (blocks [0,NTOK)) + wq cast (next 3072 blocks)
//    + wo cast (last 1024 blocks). 3 launches -> 1. (Proven round 6.)
// ---------------------------------------------------------------------------
__global__ __launch_bounds__(256) void prep_kernel(const float* __restrict__ x,
                                                   const float* __restrict__ w,
                                                   const float* __restrict__ b,
                                                   u16* __restrict__ h,
                                                   const float* __restrict__ wq_in,
                                                   u16* __restrict__ wq_out,
                                                   const float* __restrict__ wo_in,
                                                   u16* __restrict__ wo_out) {
    __shared__ float red[4];
    int blk = blockIdx.x;
    int t = threadIdx.x;
    if (blk < NTOK) {
        // ---- LayerNorm row ----
        const float* xr = x + (size_t)blk * D;
        float v[4];
        float s = 0.f;
        #pragma unroll
        for (int i = 0; i < 4; i++) { v[i] = xr[t + 256 * i]; s += v[i]; }
        float mean = block_reduce_sum(s, red) * (1.0f / 1024.0f);
        float ss = 0.f;
        #pragma unroll
        for (int i = 0; i < 4; i++) { float d = v[i] - mean; ss += d * d; }
        float var = block_reduce_sum(ss, red) * (1.0f / 1024.0f);
        float rstd = rsqrtf(var + 1e-5f);
        u16* hr = h + (size_t)blk * D;
        #pragma unroll
        for (int i = 0; i < 4; i++) {
            int c = t + 256 * i;
            hr[c] = (u16)f2bf((v[i] - mean) * rstd * w[c] + b[c]);
        }
    } else if (blk < NTOK + 3072) {
        // ---- wq fp32 -> bf16 ----
        int i = ((blk - NTOK) * 256 + t) * 4;
        float4 f = *(const float4*)(wq_in + i);
        s16x4 o4;
        o4[0] = f2bf(f.x); o4[1] = f2bf(f.y); o4[2] = f2bf(f.z); o4[3] = f2bf(f.w);
        *(s16x4*)(wq_out + i) = o4;
    } else {
        // ---- wo fp32 -> bf16 ----
        int i = ((blk - NTOK - 3072) * 256 + t) * 4;
        float4 f = *(const float4*)(wo_in + i);
        s16x4 o4;
        o4[0] = f2bf(f.x); o4[1] = f2bf(f.y); o4[2] = f2bf(f.z); o4[3] = f2bf(f.w);
        *(s16x4*)(wo_out + i) = o4;
    }
}

// ---------------------------------------------------------------------------
// 2) bf16 MFMA GEMM, m97 structure BK=64: C = A @ B^T + bias (+R).
//    Round-8: QKV on this = -10 us vs BK=32 (barrier-drain count halved,
//    2x MFMA per drain; swizzled stage/rdfrag pair conflict-free).
//    Round-9: out-proj ported here too (same K=1024, template supports RES).
//    NORMK: fused k L2-normalization (wave's 64-col span == one head).
// ---------------------------------------------------------------------------
template <typename OutT, bool RES, bool NORMK>
__global__ __launch_bounds__(256) void gemm_bk64(const u16* __restrict__ A,
                                                 const u16* __restrict__ B,
                                                 const float* __restrict__ bias,
                                                 const float* __restrict__ R,
                                                 OutT* __restrict__ C,
                                                 int M, int N, int K) {
    __shared__ u16 As[128 * 64];   // 16 KB, swizzled 128B rows
    __shared__ u16 Bs[128 * 64];
    int tid = threadIdx.x, wave = tid >> 6, lane = tid & 63;
    int quad = lane >> 4, l16 = lane & 15;
    int wm = (wave & 1) * 64, wn = (wave >> 1) * 64;
    int rowBase = blockIdx.y * 128, colBase = blockIdx.x * 128;

    f32x4 acc[4][4];
    #pragma unroll
    for (int i = 0; i < 4; i++)
        #pragma unroll
        for (int j = 0; j < 4; j++)
            acc[i][j] = (f32x4){0.f, 0.f, 0.f, 0.f};

    for (int k0 = 0; k0 < K; k0 += 64) {
        __syncthreads();
        #pragma unroll
        for (int i = 0; i < 4; i++) {
            int c = wave * 4 + i;
            int baserow = c * 8;
            int row = baserow + (lane >> 3);
            int colb = ((lane & 7) * 16) ^ ((row & 7) << 4);
            const u16* ga = A + (size_t)(rowBase + row) * K + k0 + (colb >> 1);
            async_lds16(ga, &As[baserow * 64]);
            const u16* gb = B + (size_t)(colBase + row) * K + k0 + (colb >> 1);
            async_lds16(gb, &Bs[baserow * 64]);
        }
        __syncthreads();

        s16x8 af[4][2], bfr[4][2];
        #pragma unroll
        for (int t = 0; t < 4; t++)
            #pragma unroll
            for (int kk = 0; kk < 2; kk++) {
                af[t][kk]  = rdfrag(As, wm + t * 16 + l16, kk, quad);
                bfr[t][kk] = rdfrag(Bs, wn + t * 16 + l16, kk, quad);
            }
        #pragma unroll
        for (int kk = 0; kk < 2; kk++)
            #pragma unroll
            for (int mt = 0; mt < 4; mt++)
                #pragma unroll
                for (int nt = 0; nt < 4; nt++)
                    acc[mt][nt] = __builtin_amdgcn_mfma_f32_16x16x32_bf16(
                        af[mt][kk], bfr[nt][kk], acc[mt][nt], 0, 0, 0);
    }

    // wave-uniform: does this wave's 64-col span hold k values?
    bool normk = NORMK && (colBase + wn) >= 1024 && (colBase + wn) < 2048;

    #pragma unroll
    for (int mt = 0; mt < 4; mt++) {
        float vals[4][4];   // [nt][r]
        #pragma unroll
        for (int nt = 0; nt < 4; nt++) {
            int gn = colBase + wn + nt * 16 + l16;
            float bv = bias[gn];
            #pragma unroll
            for (int r = 0; r < 4; r++) {
                float val = acc[mt][nt][r] + bv;
                if (RES) {
                    int gm = rowBase + wm + mt * 16 + quad * 4 + r;
                    val += R[(size_t)gm * N + gn];
                }
                vals[nt][r] = val;
            }
        }
        if (normk) {
            #pragma unroll
            for (int r = 0; r < 4; r++) {
                float ssq = 0.f;
                #pragma unroll
                for (int nt = 0; nt < 4; nt++) ssq = fmaf(vals[nt][r], vals[nt][r], ssq);
                ssq += __shfl_xor(ssq, 1, 64);
                ssq += __shfl_xor(ssq, 2, 64);
                ssq += __shfl_xor(ssq, 4, 64);
                ssq += __shfl_xor(ssq, 8, 64);
                float inv = 1.0f / fmaxf(sqrtf(ssq), 1e-12f);
                #pragma unroll
                for (int nt = 0; nt < 4; nt++) vals[nt][r] *= inv;
            }
        }
        #pragma unroll
        for (int nt = 0; nt < 4; nt++) {
            int gn = colBase + wn + nt * 16 + l16;
            int gm0 = rowBase + wm + mt * 16 + quad * 4;
            #pragma unroll
            for (int r = 0; r < 4; r++) {
                if constexpr (sizeof(OutT) == 2)
                    C[(size_t)(gm0 + r) * N + gn] = (OutT)f2bf(vals[nt][r]);
                else
                    C[(size_t)(gm0 + r) * N + gn] = vals[nt][r];
            }
        }
    }
}

// ---------------------------------------------------------------------------
// 3) MFMA flash attention v9 (proven rounds 6-8: ~84.5-85.6 us, occ ~33%).
//    Block = one (b,h) x 256 q-rows; 8 waves x 32 q-rows (2 row-tiles of 16).
//    Grid 512, 512 threads -> 2 blocks/CU = 4 waves/SIMD. K/V staging by
//    waves 0-3 at the v6 addresses (HBM fetch + LDS-write work unchanged).
//    MfmaUtil 40 + VALUBusy 49 ~= 90% combined issue -- near saturation;
//    further gains require the subtiled-V tr_read redesign (queued).
// ---------------------------------------------------------------------------
__global__ __launch_bounds__(512, 4) void mha_kernel(const u16* __restrict__ qkv,
                                                     u16* __restrict__ out) {
    __shared__ u16 Ks[64 * 64];       // swizzled [row][8 chunks of 8 u16]
    constexpr int VS = 68;            // Vt row stride (u16): 136 B
    __shared__ u16 Vt[64 * VS];       // V tile [d][key] (transposed)

    int bh = blockIdx.x & 63;         // XCD-locality swizzle
    int qt = blockIdx.x >> 6;         // 8 q-tiles of 256 rows
    int b  = bh >> 4, h = bh & 15;
    int tid = threadIdx.x;
    int wave = tid >> 6, lane = tid & 63;
    int quad = lane >> 4, l16 = lane & 15;

    const size_t rs = 3072;
    constexpr float SCL = 11.5415605f;   // 8 * log2(e)

    // --- Q frags: 2 row-tiles of 16 per wave; normalize + fold SCL ---
    s16x8 aq[2][2];
    #pragma unroll
    for (int rt = 0; rt < 2; rt++) {
        const u16* qb = qkv + ((size_t)(b * SEQ) + qt * 256 + wave * 32 + rt * 16 + l16) * rs + h * 64;
        s16x8 r0 = *(const s16x8*)(qb + quad * 8);
        s16x8 r1 = *(const s16x8*)(qb + 32 + quad * 8);
        float f0[8], f1[8], ss = 0.f;
        #pragma unroll
        for (int i = 0; i < 8; i++) { f0[i] = bf2f((u16)r0[i]); ss = fmaf(f0[i], f0[i], ss); }
        #pragma unroll
        for (int i = 0; i < 8; i++) { f1[i] = bf2f((u16)r1[i]); ss = fmaf(f1[i], f1[i], ss); }
        ss += __shfl_xor(ss, 16, 64);
        ss += __shfl_xor(ss, 32, 64);
        float inv = SCL / fmaxf(sqrtf(ss), 1e-12f);
        #pragma unroll
        for (int i = 0; i < 8; i++) {
            aq[rt][0][i] = f2bf(f0[i] * inv);
            aq[rt][1][i] = f2bf(f1[i] * inv);
        }
    }

    const f32x4 cinit = {-SCL, -SCL, -SCL, -SCL};
    f32x4 o2[2][4];    // O^T frags: lane holds d=ht*16+quad*4+r, qrow=l16
    f32x4 osum[2];     // ones-tile accumulators: lsum[rt] = osum[rt][0]
    #pragma unroll
    for (int rt = 0; rt < 2; rt++) {
        #pragma unroll
        for (int ht = 0; ht < 4; ht++) o2[rt][ht] = (f32x4){0.f, 0.f, 0.f, 0.f};
        osum[rt] = (f32x4){0.f, 0.f, 0.f, 0.f};
    }
    s16x8 ones;
    #pragma unroll
    for (int i = 0; i < 8; i++) ones[i] = (short)0x3F80;   // bf16 1.0

    // staging assignments: waves 0-3 only, identical addresses to v6
    bool stager = (tid < 256);
    int st = tid & 255;
    int skey = st >> 2, c4 = st & 3;              // K: row skey, chunks 2c4,2c4+1
    int ksw  = skey & 7;                          // K swizzle key
    int vp2 = st >> 3, dc = (st & 7) * 8;         // V: key pair (2vp2,2vp2+1)
    const u16* kglob  = qkv + ((size_t)(b * SEQ) + skey) * rs + 1024 + h * 64 + c4 * 16;
    const u16* vglob0 = qkv + ((size_t)(b * SEQ) + 2 * vp2) * rs + 2048 + h * 64 + dc;
    u16* kdst0 = &Ks[skey * 64 + ((2 * c4)     ^ ksw) * 8];
    u16* kdst1 = &Ks[skey * 64 + ((2 * c4 + 1) ^ ksw) * 8];
    u32* vt32 = (u32*)&Vt[0];

    // prefetch tile 0 (stagers only)
    s16x8 kr0{}, kr1{}, vr0{}, vr1{};
    if (stager) {
        kr0 = ((const s16x8*)kglob)[0];
        kr1 = ((const s16x8*)kglob)[1];
        vr0 = *(const s16x8*)(vglob0);
        vr1 = *(const s16x8*)(vglob0 + rs);
    }

    int swz = l16 & 7;   // read-side swizzle key (row & 7 = l16 & 7)

    for (int kb = 0; kb < SEQ / 64; kb++) {
        __syncthreads();   // previous tile's LDS reads done
        if (stager) {
            *(s16x8*)kdst0 = kr0;
            *(s16x8*)kdst1 = kr1;
            #pragma unroll
            for (int i = 0; i < 8; i++) {
                u32 pk = (u32)(u16)vr0[i] | ((u32)(u16)vr1[i] << 16);
                vt32[(dc + i) * (VS / 2) + vp2] = pk;
            }
        }
        __syncthreads();

        // prefetch next tile into regs (stagers; overlaps compute of all waves)
        if (stager && kb < SEQ / 64 - 1) {
            const u16* kp = kglob + (size_t)(kb + 1) * 64 * rs;
            const u16* vp = vglob0 + (size_t)(kb + 1) * 64 * rs;
            kr0 = ((const s16x8*)kp)[0];
            kr1 = ((const s16x8*)kp)[1];
            vr0 = *(const s16x8*)(vp);
            vr1 = *(const s16x8*)(vp + rs);
        }

        // --- S^T = K.(SCL*Q)^T - SCL ; p = exp2(s); packed P in regs ---
        s16x4 pfr[2][4];      // [rt][t]: P[qrow=l16][key=t*16+quad*4+{0..3}]
        #pragma unroll
        for (int t = 0; t < 4; t++) {
            const u16* krow = &Ks[(t * 16 + l16) * 64];
            s16x8 bk0 = *(const s16x8*)(krow + ((0 + quad) ^ swz) * 8);
            s16x8 bk1 = *(const s16x8*)(krow + ((4 + quad) ^ swz) * 8);
            #pragma unroll
            for (int rt = 0; rt < 2; rt++) {
                f32x4 s = cinit;
                s = __builtin_amdgcn_mfma_f32_16x16x32_bf16(bk0, aq[rt][0], s, 0, 0, 0);
                s = __builtin_amdgcn_mfma_f32_16x16x32_bf16(bk1, aq[rt][1], s, 0, 0, 0);
                uint2 pk2;
                pk2.x = pack_bf16_pair(EXP2(s[0]), EXP2(s[1]));
                pk2.y = pack_bf16_pair(EXP2(s[2]), EXP2(s[3]));
                pfr[rt][t] = __builtin_bit_cast(s16x4, pk2);
            }
        }

        // --- O^T += V^T.P^T (+ ones sum tile), permuted key order ---
        #pragma unroll
        for (int pr = 0; pr < 2; pr++) {
            int tA = pr * 2, tB = pr * 2 + 1;
            s16x8 bp[2];
            #pragma unroll
            for (int rt = 0; rt < 2; rt++)
                bp[rt] = __builtin_shufflevector(pfr[rt][tA], pfr[rt][tB],
                                                 0, 1, 2, 3, 4, 5, 6, 7);
            #pragma unroll
            for (int ht = 0; ht < 4; ht++) {
                const u16* vrow = &Vt[(ht * 16 + l16) * VS];
                s16x4 va = *(const s16x4*)(vrow + tA * 16 + quad * 4);
                s16x4 vb = *(const s16x4*)(vrow + tB * 16 + quad * 4);
                s16x8 vfr = __builtin_shufflevector(va, vb, 0, 1, 2, 3, 4, 5, 6, 7);
                #pragma unroll
                for (int rt = 0; rt < 2; rt++)
                    o2[rt][ht] = __builtin_amdgcn_mfma_f32_16x16x32_bf16(
                        vfr, bp[rt], o2[rt][ht], 0, 0, 0);
            }
            #pragma unroll
            for (int rt = 0; rt < 2; rt++)
                osum[rt] = __builtin_amdgcn_mfma_f32_16x16x32_bf16(
                    ones, bp[rt], osum[rt], 0, 0, 0);
        }
    }

    // --- epilogue: lane owns qrow=l16 (per rt), d = ht*16+quad*4+r ---
    #pragma unroll
    for (int rt = 0; rt < 2; rt++) {
        float inv = 1.0f / osum[rt][0];
        int orow = b * SEQ + qt * 256 + wave * 32 + rt * 16 + l16;
        u16* op = out + (size_t)orow * D + h * 64 + quad * 4;
        #pragma unroll
        for (int ht = 0; ht < 4; ht++) {
            f32x4 v = o2[rt][ht];
            u32 lo = pack_bf16_pair(v[0] * inv, v[1] * inv);
            u32 hi = pack_bf16_pair(v[2] * inv, v[3] * inv);
            uint2 pk = {lo, hi};
            *(uint2*)(op + ht * 16) = pk;
        }
    }
}

// ---------------------------------------------------------------------------
// launch
// ---------------------------------------------------------------------------
extern "C" void kernel_launch(void* const* d_in, const int* in_sizes, int n_in,
                              void* d_out, int out_size, void* d_ws, size_t ws_size,
                              hipStream_t stream) {
    const float* x     = (const float*)d_in[0];
    const float* ln_w  = (const float*)d_in[1];
    const float* ln_b  = (const float*)d_in[2];
    const float* qkv_w = (const float*)d_in[3];
    const float* qkv_b = (const float*)d_in[4];
    const float* out_w = (const float*)d_in[5];
    const float* out_b = (const float*)d_in[6];
    float* y = (float*)d_out;

    // workspace carve-up: qkv 48MB | h 16MB | wq 6MB | wo 2MB
    char* ws = (char*)d_ws;
    u16* qkv = (u16*)ws;
    u16* h   = (u16*)(ws + (size_t)48 * 1024 * 1024);
    u16* wq  = (u16*)(ws + (size_t)64 * 1024 * 1024);
    u16* wo  = (u16*)(ws + (size_t)70 * 1024 * 1024);
    u16* attn_out = h;

    // fused LN + weight casts (1 launch instead of 3)
    prep_kernel<<<NTOK + 3072 + 1024, 256, 0, stream>>>(x, ln_w, ln_b, h,
                                                        qkv_w, wq, out_w, wo);

    // QKV GEMM (m97 BK=64) with fused k L2-normalization in the epilogue
    {
        dim3 grid(3 * D / 128, NTOK / 128);
        gemm_bk64<u16, false, true><<<grid, 256, 0, stream>>>(h, wq, qkv_b, nullptr,
                                                              qkv, NTOK, 3 * D, D);
    }

    // flash attention v9
    mha_kernel<<<BATCH * NH * (SEQ / 256), 512, 0, stream>>>(qkv, attn_out);

    // out-proj GEMM (m97 BK=64, 512 blocks full-chip) + residual
    {
        dim3 grid(D / 128, NTOK / 128);
        gemm_bk64<float, true, false><<<grid, 256, 0, stream>>>(attn_out, wo, out_b,
                                                                x, y, NTOK, D, D);
    }
}